// Round 1
// baseline (4652.264 us; speedup 1.0000x reference)
//
#include <hip/hip_runtime.h>
#include <hip/hip_bf16.h>

#define D_   512
#define HID_ 2048
#define NH_  8
#define DH_  64
#define L_   6
#define B_   8
#define S_   512
#define T_   512
#define M_   4096            // B_*S_ rows
#define MD_  (M_ * D_)
#define QSTR 1536            // packed QKV row stride

typedef unsigned short ushort_t;
typedef __attribute__((ext_vector_type(8))) short bf16x8;
typedef __attribute__((ext_vector_type(4))) float f32x4;

__device__ __forceinline__ float bf2f(unsigned short u) {
    union { unsigned int i; float f; } x; x.i = ((unsigned int)u) << 16; return x.f;
}
__device__ __forceinline__ unsigned short f2bf(float f) {
    union { float f; unsigned int u; } x; x.f = f;
    unsigned int r = (x.u + 0x7fffu + ((x.u >> 16) & 1u)) >> 16;
    return (unsigned short)r;
}
// Dual-dtype param loads: mode==1 -> storage f32, mode==0 -> bf16.
__device__ __forceinline__ float ldp(const void* p, size_t i, int mode) {
    return mode ? ((const float*)p)[i] : bf2f(((const unsigned short*)p)[i]);
}

// async global->LDS, 16B per lane; lds dest must be wave-uniform base (+lane*16 implicit)
typedef __attribute__((address_space(1))) const unsigned int GAS_u32;
typedef __attribute__((address_space(3))) unsigned int LAS_u32;
__device__ __forceinline__ void gload16(const void* g, void* l) {
    __builtin_amdgcn_global_load_lds((GAS_u32*)g, (LAS_u32*)l, 16, 0, 0);
}

// ---------------- dtype probe ----------------
__global__ __launch_bounds__(256) void detect_kernel(const void* em, int* flagp) {
    __shared__ int big, zc;
    if (threadIdx.x == 0) { big = 0; zc = 0; }
    __syncthreads();
    const unsigned short* u = (const unsigned short*)em;
    int lbig = 0, lzc = 0;
    for (int i = threadIdx.x; i < 2048; i += 256) {
        unsigned short x = u[512 + i];
        float v = bf2f(x);
        if (!(fabsf(v) < 1000.0f)) lbig = 1;
        if ((((512 + i) & 1) == 0) && ((x & 0x7fff) == 0)) lzc++;
    }
    if (lbig) atomicOr(&big, 1);
    atomicAdd(&zc, lzc);
    __syncthreads();
    if (threadIdx.x == 0) flagp[0] = (big || zc >= 1000) ? 1 : 0;
}

// ---------------- embedding + PE: writes f32 stream + bf16 shadow ----------------
__global__ __launch_bounds__(256) void embed_pe_kernel(const int* __restrict__ tok,
        const void* __restrict__ em, float* __restrict__ out,
        unsigned short* __restrict__ outb, const int* __restrict__ flagp)
{
    const int mode = flagp[0];
    int idx = blockIdx.x * 256 + threadIdx.x;
    int d   = idx & (D_ - 1);
    int row = idx >> 9;
    int s   = row & (S_ - 1);
    int t   = tok[row];
    float e = ldp(em, (size_t)t * D_ + d, mode);
    int d2  = d & ~1;
    float div = expf((float)d2 * (-9.210340371976184f / (float)D_));
    float a   = (float)s * div;
    float pe  = (d & 1) ? cosf(a) : sinf(a);
    float v   = e + pe;
    out[idx]  = v;
    outb[idx] = f2bf(v);
}

// ---------------- bf16 MFMA GEMM, software-pipelined ----------------
// C[M,N] = A[M,K](bf16) @ W[K,N](bf16 or f32 per mode) + bias.
// Block 256 thr = 4 waves (2x2). Tile TM x 128, BK=32.
// Double-buffered LDS, one barrier per K-step:
//   iter t: issue A(t+1) via global_load_lds + W(t+1) into regs,
//           MFMA on tile t (no vmem dependency), convert+ds_write W(t+1), barrier.
// As: linear [TM][32] bf16 (required by global_load_lds; b128 reads at throughput floor).
// Bs: [128][40] (pad->40, 2-way read aliasing only).
template<int TMT>
__global__ __launch_bounds__(256) void mfma_gemm(
        const unsigned short* __restrict__ A, int K,
        const void* __restrict__ W, size_t woff, int nsub,
        const void* __restrict__ bias, size_t boff,
        void* __restrict__ C, int ldc, int cmode /*0=f32,1=bf16*/, int relu,
        const int* __restrict__ flagp)
{
    constexpr int TM     = TMT * 32;
    constexpr int ALOADS = (TM * 64) / 1024;   // wave-instrs per A tile (8 or 4)
    constexpr int APW    = ALOADS / 4;         // per wave (2 or 1)
    __shared__ unsigned short As[2][TM * 32];
    __shared__ unsigned short Bs[2][128 * 40];

    const int mode = __builtin_amdgcn_readfirstlane(flagp[0]);
    const int tid  = threadIdx.x;
    const int m0   = blockIdx.y * TM;
    const int n0   = blockIdx.x * 128;

    const size_t wbase = woff + (size_t)(n0 / nsub) * (size_t)K * nsub + (n0 % nsub);

    const int lane = tid & 63;
    const int wave = tid >> 6;

    // A staging via global_load_lds: lane covers 16B at lds byte (wave*APW+u)*1024 + lane*16
    // linear [TM][64B]: row = off>>6, kbyte = off&63
    int arow[APW], akb[APW];
#pragma unroll
    for (int u = 0; u < APW; ++u) {
        int off = (wave * APW + u) * 1024 + lane * 16;
        arow[u] = off >> 6;
        akb[u]  = off & 63;
    }

    // W staging assignment: thread covers 8k x 2n patch
    const int n0t = 2 * (tid & 63);
    const int kb  = 8 * (tid >> 6);

    // wave/lane for MFMA
    const int ln = lane & 15;
    const int q  = lane >> 4;
    const int wm = (wave >> 1) * (TMT * 16);
    const int wn = (wave & 1) * 64;

    f32x4 acc[TMT][4];
#pragma unroll
    for (int i = 0; i < TMT; ++i)
#pragma unroll
        for (int j = 0; j < 4; ++j) acc[i][j] = (f32x4)0.0f;

    unsigned int wv[16];   // W prefetch regs (8 used in bf16 mode, 16 in f32 mode)

    auto stageA = [&](int t, int buf) {
#pragma unroll
        for (int u = 0; u < APW; ++u) {
            const unsigned short* src = A + (size_t)(m0 + arow[u]) * K + t * 32 + (akb[u] >> 1);
            gload16(src, &As[buf][(wave * APW + u) * 512]);
        }
    };
    auto loadW = [&](int t) {
        int k0 = t * 32;
        if (mode == 0) {
            const unsigned short* wp = (const unsigned short*)W + wbase;
#pragma unroll
            for (int r = 0; r < 8; ++r)
                wv[r] = *reinterpret_cast<const unsigned int*>(
                    wp + (size_t)(k0 + kb + r) * nsub + n0t);
        } else {
            const float* wp = (const float*)W + wbase;
#pragma unroll
            for (int r = 0; r < 8; ++r) {
                uint2 f = *reinterpret_cast<const uint2*>(
                    wp + (size_t)(k0 + kb + r) * nsub + n0t);
                wv[2 * r] = f.x; wv[2 * r + 1] = f.y;
            }
        }
    };
    auto writeB = [&](int buf) {
        unsigned int lo[4], hi[4];
        if (mode == 0) {
#pragma unroll
            for (int p = 0; p < 4; ++p) {
                lo[p] = (wv[2*p] & 0xffffu) | (wv[2*p+1] << 16);
                hi[p] = (wv[2*p] >> 16) | (wv[2*p+1] & 0xffff0000u);
            }
        } else {
            unsigned short a[8], b[8];
#pragma unroll
            for (int r = 0; r < 8; ++r) {
                union { unsigned int u; float f; } x, y;
                x.u = wv[2*r]; y.u = wv[2*r+1];
                a[r] = f2bf(x.f); b[r] = f2bf(y.f);
            }
#pragma unroll
            for (int p = 0; p < 4; ++p) {
                lo[p] = (unsigned int)a[2*p] | ((unsigned int)a[2*p+1] << 16);
                hi[p] = (unsigned int)b[2*p] | ((unsigned int)b[2*p+1] << 16);
            }
        }
        *reinterpret_cast<uint4*>(&Bs[buf][(n0t + 0) * 40 + kb]) = make_uint4(lo[0], lo[1], lo[2], lo[3]);
        *reinterpret_cast<uint4*>(&Bs[buf][(n0t + 1) * 40 + kb]) = make_uint4(hi[0], hi[1], hi[2], hi[3]);
    };
    auto compute = [&](int buf) {
        bf16x8 af[TMT], bfv[4];
#pragma unroll
        for (int i = 0; i < TMT; ++i)
            af[i] = *reinterpret_cast<const bf16x8*>(&As[buf][(wm + i * 16 + ln) * 32 + q * 8]);
#pragma unroll
        for (int j = 0; j < 4; ++j)
            bfv[j] = *reinterpret_cast<const bf16x8*>(&Bs[buf][(wn + j * 16 + ln) * 40 + q * 8]);
#pragma unroll
        for (int i = 0; i < TMT; ++i)
#pragma unroll
            for (int j = 0; j < 4; ++j)
                acc[i][j] = __builtin_amdgcn_mfma_f32_16x16x32_bf16(af[i], bfv[j], acc[i][j], 0, 0, 0);
    };

    const int NT = K >> 5;

    // prologue: tile 0
    stageA(0, 0);
    loadW(0);
    writeB(0);            // compiler inserts vmcnt wait for wv
    __syncthreads();      // drains gload_lds (vmcnt 0) + ds_writes

    for (int t = 0; t < NT; ++t) {
        int cur = t & 1;
        if (t + 1 < NT) {
            stageA(t + 1, cur ^ 1);   // async into other LDS buffer
            loadW(t + 1);             // async into regs
        }
        compute(cur);                 // ds_read + MFMA, no vmem dependency
        if (t + 1 < NT) writeB(cur ^ 1);
        __syncthreads();
    }

    // epilogue: bias (+relu), store f32 or bf16
    float bj[4];
#pragma unroll
    for (int j = 0; j < 4; ++j)
        bj[j] = ldp(bias, boff + (size_t)n0 + wn + j * 16 + ln, mode);
#pragma unroll
    for (int i = 0; i < TMT; ++i) {
#pragma unroll
        for (int j = 0; j < 4; ++j) {
            int n = n0 + wn + j * 16 + ln;
#pragma unroll
            for (int r = 0; r < 4; ++r) {
                int m = m0 + wm + i * 16 + q * 4 + r;
                float v = acc[i][j][r] + bj[j];
                if (relu) v = fmaxf(v, 0.0f);
                if (cmode == 0) ((float*)C)[(size_t)m * ldc + n] = v;
                else            ((unsigned short*)C)[(size_t)m * ldc + n] = f2bf(v);
            }
        }
    }
}

// ---------------- flash attention (bf16 packed QKV in, bf16 CTX out) ----------------
#define LSTR 68
__global__ __launch_bounds__(256) void fattn_kernel(const unsigned short* __restrict__ QKV,
        const int* __restrict__ kv_tok, unsigned short* __restrict__ O,
        int Sk, int causal)
{
    __shared__ float Qs[64 * LSTR];    // [d][q]
    __shared__ float KVs[64 * LSTR];   // K: [d][k]; V: [k][d]
    __shared__ float Ps[64 * LSTR];    // [q][k]
    int tid = threadIdx.x;
    int bid = blockIdx.x;
    int tq = bid & 7;
    int h  = (bid >> 3) & 7;
    int b  = bid >> 6;
    int q0 = tq * 64;
    const int qg = tid >> 4, kg = tid & 15;
    const int sr = tid >> 2, sc0 = (tid & 3) * 16;

    {   // stage Q transposed
        const unsigned short* p = QKV + (size_t)(b * 512 + q0 + sr) * QSTR + h * DH_ + sc0;
        uint4 u0 = *reinterpret_cast<const uint4*>(p);
        uint4 u1 = *reinterpret_cast<const uint4*>(p + 8);
        unsigned int w[8] = {u0.x, u0.y, u0.z, u0.w, u1.x, u1.y, u1.z, u1.w};
#pragma unroll
        for (int e = 0; e < 8; ++e) {
            Qs[(sc0 + 2 * e + 0) * LSTR + sr] = bf2f((unsigned short)(w[e] & 0xffffu));
            Qs[(sc0 + 2 * e + 1) * LSTR + sr] = bf2f((unsigned short)(w[e] >> 16));
        }
    }

    float m[4], l[4], o[4][4];
#pragma unroll
    for (int i = 0; i < 4; ++i) {
        m[i] = -INFINITY; l[i] = 0.0f;
#pragma unroll
        for (int j = 0; j < 4; ++j) o[i][j] = 0.0f;
    }

    const int nkt = causal ? (tq + 1) : (Sk >> 6);
    for (int kt = 0; kt < nkt; ++kt) {
        int k0 = kt * 64;
        __syncthreads();
        {   // stage K transposed (cols 512..1023 of QKV)
            const unsigned short* p = QKV + (size_t)(b * Sk + k0 + sr) * QSTR + 512 + h * DH_ + sc0;
            uint4 u0 = *reinterpret_cast<const uint4*>(p);
            uint4 u1 = *reinterpret_cast<const uint4*>(p + 8);
            unsigned int w[8] = {u0.x, u0.y, u0.z, u0.w, u1.x, u1.y, u1.z, u1.w};
#pragma unroll
            for (int e = 0; e < 8; ++e) {
                KVs[(sc0 + 2 * e + 0) * LSTR + sr] = bf2f((unsigned short)(w[e] & 0xffffu));
                KVs[(sc0 + 2 * e + 1) * LSTR + sr] = bf2f((unsigned short)(w[e] >> 16));
            }
        }
        __syncthreads();

        float s[4][4] = {};
        for (int d = 0; d < 64; ++d) {
            float4 a4 = *reinterpret_cast<const float4*>(&Qs[d * LSTR + qg * 4]);
            float4 b4 = *reinterpret_cast<const float4*>(&KVs[d * LSTR + kg * 4]);
            float a[4] = {a4.x, a4.y, a4.z, a4.w};
            float bb[4] = {b4.x, b4.y, b4.z, b4.w};
#pragma unroll
            for (int i = 0; i < 4; ++i)
#pragma unroll
                for (int j = 0; j < 4; ++j)
                    s[i][j] = fmaf(a[i], bb[j], s[i][j]);
        }

        int kbase = k0 + kg * 4;
        int tk[4];
#pragma unroll
        for (int j = 0; j < 4; ++j) tk[j] = kv_tok[b * Sk + kbase + j];
#pragma unroll
        for (int i = 0; i < 4; ++i) {
            int qrow = q0 + qg * 4 + i;
#pragma unroll
            for (int j = 0; j < 4; ++j) {
                bool masked = (causal && (kbase + j > qrow)) || (tk[j] == 0);
                s[i][j] = masked ? -INFINITY : s[i][j] * 0.125f;
            }
        }

#pragma unroll
        for (int i = 0; i < 4; ++i) {
            float tm = fmaxf(fmaxf(s[i][0], s[i][1]), fmaxf(s[i][2], s[i][3]));
            tm = fmaxf(tm, __shfl_xor(tm, 1, 16));
            tm = fmaxf(tm, __shfl_xor(tm, 2, 16));
            tm = fmaxf(tm, __shfl_xor(tm, 4, 16));
            tm = fmaxf(tm, __shfl_xor(tm, 8, 16));
            float mnew = fmaxf(m[i], tm);
            float alpha = (mnew == -INFINITY) ? 1.0f : __expf(m[i] - mnew);
            float p[4];
#pragma unroll
            for (int j = 0; j < 4; ++j)
                p[j] = (s[i][j] == -INFINITY) ? 0.0f : __expf(s[i][j] - mnew);
            float4 p4; p4.x = p[0]; p4.y = p[1]; p4.z = p[2]; p4.w = p[3];
            *reinterpret_cast<float4*>(&Ps[(qg * 4 + i) * LSTR + kg * 4]) = p4;
            float rs = p[0] + p[1] + p[2] + p[3];
            rs += __shfl_xor(rs, 1, 16);
            rs += __shfl_xor(rs, 2, 16);
            rs += __shfl_xor(rs, 4, 16);
            rs += __shfl_xor(rs, 8, 16);
            l[i] = l[i] * alpha + rs;
            m[i] = mnew;
#pragma unroll
            for (int j = 0; j < 4; ++j) o[i][j] *= alpha;
        }
        __syncthreads();

        {   // stage V natural [k][d] (cols 1024..1535)
            const unsigned short* p = QKV + (size_t)(b * Sk + k0 + sr) * QSTR + 1024 + h * DH_ + sc0;
            uint4 u0 = *reinterpret_cast<const uint4*>(p);
            uint4 u1 = *reinterpret_cast<const uint4*>(p + 8);
            unsigned int w[8] = {u0.x, u0.y, u0.z, u0.w, u1.x, u1.y, u1.z, u1.w};
#pragma unroll
            for (int e = 0; e < 8; ++e) {
                KVs[sr * LSTR + sc0 + 2 * e + 0] = bf2f((unsigned short)(w[e] & 0xffffu));
                KVs[sr * LSTR + sc0 + 2 * e + 1] = bf2f((unsigned short)(w[e] >> 16));
            }
        }
        __syncthreads();

        for (int k = 0; k < 64; ++k) {
            float4 v4 = *reinterpret_cast<const float4*>(&KVs[k * LSTR + kg * 4]);
            float vv[4] = {v4.x, v4.y, v4.z, v4.w};
            float p0 = Ps[(qg * 4 + 0) * LSTR + k];
            float p1 = Ps[(qg * 4 + 1) * LSTR + k];
            float p2 = Ps[(qg * 4 + 2) * LSTR + k];
            float p3 = Ps[(qg * 4 + 3) * LSTR + k];
#pragma unroll
            for (int j = 0; j < 4; ++j) {
                o[0][j] = fmaf(p0, vv[j], o[0][j]);
                o[1][j] = fmaf(p1, vv[j], o[1][j]);
                o[2][j] = fmaf(p2, vv[j], o[2][j]);
                o[3][j] = fmaf(p3, vv[j], o[3][j]);
            }
        }
    }

#pragma unroll
    for (int i = 0; i < 4; ++i) {
        float inv = (l[i] > 0.0f) ? 1.0f / l[i] : 0.0f;
        ushort4 r;
        r.x = f2bf(o[i][0] * inv); r.y = f2bf(o[i][1] * inv);
        r.z = f2bf(o[i][2] * inv); r.w = f2bf(o[i][3] * inv);
        *reinterpret_cast<ushort4*>(
            &O[(size_t)(b * 512 + q0 + qg * 4 + i) * D_ + h * DH_ + kg * 4]) = r;
    }
}

// ---------------- residual add + LayerNorm: f32 stream + bf16 shadow ----------------
__global__ __launch_bounds__(256) void add_ln_kernel(float* __restrict__ X,
        unsigned short* __restrict__ Xb,
        const float* __restrict__ R, const void* __restrict__ ln, size_t goff,
        const int* __restrict__ flagp)
{
    const int mode = flagp[0];
    __shared__ float red[256];
    int row = blockIdx.x, tid = threadIdx.x;
    size_t base = (size_t)row * D_;
    float v0 = X[base + tid] + R[base + tid];
    float v1 = X[base + 256 + tid] + R[base + 256 + tid];
    red[tid] = v0 + v1; __syncthreads();
    for (int o = 128; o > 0; o >>= 1) {
        if (tid < o) red[tid] += red[tid + o];
        __syncthreads();
    }
    float mu = red[0] * (1.0f / (float)D_);
    __syncthreads();
    float d0 = v0 - mu, d1 = v1 - mu;
    red[tid] = d0 * d0 + d1 * d1; __syncthreads();
    for (int o = 128; o > 0; o >>= 1) {
        if (tid < o) red[tid] += red[tid + o];
        __syncthreads();
    }
    float inv = rsqrtf(red[0] * (1.0f / (float)D_) + 1e-5f);
    float r0 = d0 * inv * ldp(ln, goff + tid, mode)       + ldp(ln, goff + D_ + tid, mode);
    float r1 = d1 * inv * ldp(ln, goff + 256 + tid, mode) + ldp(ln, goff + D_ + 256 + tid, mode);
    X[base + tid] = r0;         Xb[base + tid] = f2bf(r0);
    X[base + 256 + tid] = r1;   Xb[base + 256 + tid] = f2bf(r1);
}

// ---------------- f32 -> output (bf16 or f32 per mode) ----------------
__global__ __launch_bounds__(256) void to_out_kernel(const float* __restrict__ in,
        void* __restrict__ out, int n, const int* __restrict__ flagp)
{
    const int mode = flagp[0];
    int i = blockIdx.x * 256 + threadIdx.x;
    if (i < n) {
        float v = in[i];
        if (mode) ((float*)out)[i] = v;
        else      ((__hip_bfloat16*)out)[i] = __float2bfloat16(v);
    }
}

extern "C" void kernel_launch(void* const* d_in, const int* in_sizes, int n_in,
                              void* d_out, int out_size, void* d_ws, size_t ws_size,
                              hipStream_t stream) {
    const int* tin  = (const int*)d_in[0];
    const int* tout = (const int*)d_in[1];
    const void* emi = d_in[2];
    const void* emo = d_in[3];
    const void* eaw = d_in[4];
    const void* eab = d_in[5];
    const void* eln = d_in[6];
    const void* ew1 = d_in[7];
    const void* eb1 = d_in[8];
    const void* ew2 = d_in[9];
    const void* eb2 = d_in[10];
    const void* dsw = d_in[11];
    const void* dsb = d_in[12];
    const void* dcw = d_in[13];
    const void* dcb = d_in[14];
    const void* dln = d_in[15];
    const void* dw1 = d_in[16];
    const void* db1 = d_in[17];
    const void* dw2 = d_in[18];
    const void* db2 = d_in[19];

    // ws (~48 MB): flag | X,Y,P f32 | Xb,Yb bf16 | QKV(3MD)+CTX(MD) bf16 (HB overlays)
    int*   flagp = (int*)d_ws;
    float* X = (float*)d_ws + 64;
    float* Y = X + MD_;
    float* P = Y + MD_;
    unsigned short* Xb   = (unsigned short*)(P + MD_);
    unsigned short* Yb   = Xb + MD_;
    unsigned short* QKVb = Yb + MD_;
    unsigned short* CTXb = QKVb + 3 * (size_t)MD_;
    unsigned short* HB   = QKVb;   // [M_, 2048] overlays QKV+CTX during FFN

    const size_t WDD = (size_t)D_ * D_;
    const int AGRID = B_ * NH_ * 8;

    auto g4 = [&](const unsigned short* A, int K, const void* W, size_t woff, int nsub,
                  const void* bias, size_t boff, void* C, int ldc, int N, int cmode, int relu) {
        mfma_gemm<4><<<dim3(N / 128, M_ / 128), 256, 0, stream>>>(
            A, K, W, woff, nsub, bias, boff, C, ldc, cmode, relu, flagp);
    };
    auto g2 = [&](const unsigned short* A, int K, const void* W, size_t woff, int nsub,
                  const void* bias, size_t boff, void* C, int ldc, int N, int cmode, int relu) {
        mfma_gemm<2><<<dim3(N / 128, M_ / 64), 256, 0, stream>>>(
            A, K, W, woff, nsub, bias, boff, C, ldc, cmode, relu, flagp);
    };

    detect_kernel<<<1, 256, 0, stream>>>(emi, flagp);
    embed_pe_kernel<<<(M_ * D_) / 256, 256, 0, stream>>>(tin, emi, X, Xb, flagp);
    embed_pe_kernel<<<(M_ * D_) / 256, 256, 0, stream>>>(tout, emo, Y, Yb, flagp);

    // ---- encoder ----
    for (int l = 0; l < L_; ++l) {
        size_t w = (size_t)l * 4 * WDD, bb = (size_t)l * 4 * D_;
        g4(Xb, D_, eaw, w, 512, eab, bb, QKVb, QSTR, 1536, 1, 0);           // fused QKV
        fattn_kernel<<<AGRID, 256, 0, stream>>>(QKVb, tin, CTXb, S_, 0);
        g2(CTXb, D_, eaw, w + 3 * WDD, 512, eab, bb + 3 * D_, P, D_, 512, 0, 0);
        add_ln_kernel<<<M_, 256, 0, stream>>>(X, Xb, P, eln, ((size_t)l * 2 + 0) * 2 * D_, flagp);
        g4(Xb, D_, ew1, (size_t)l * D_ * HID_, 2048, eb1, (size_t)l * HID_, HB, HID_, 2048, 1, 1);
        g2(HB, HID_, ew2, (size_t)l * HID_ * D_, 512, eb2, (size_t)l * D_, P, D_, 512, 0, 0);
        add_ln_kernel<<<M_, 256, 0, stream>>>(X, Xb, P, eln, ((size_t)l * 2 + 1) * 2 * D_, flagp);
    }

    // ---- decoder ----
    for (int l = 0; l < L_; ++l) {
        size_t w = (size_t)l * 4 * WDD, bb = (size_t)l * 4 * D_;
        // self-attention (causal)
        g4(Yb, D_, dsw, w, 512, dsb, bb, QKVb, QSTR, 1536, 1, 0);
        fattn_kernel<<<AGRID, 256, 0, stream>>>(QKVb, tout, CTXb, T_, 1);
        g2(CTXb, D_, dsw, w + 3 * WDD, 512, dsb, bb + 3 * D_, P, D_, 512, 0, 0);
        add_ln_kernel<<<M_, 256, 0, stream>>>(Y, Yb, P, dln, ((size_t)l * 3 + 0) * 2 * D_, flagp);
        // cross-attention: Q from Y, K/V from X
        g2(Yb, D_, dcw, w, 512, dcb, bb, QKVb, QSTR, 512, 1, 0);            // Q -> cols 0..511
        g4(Xb, D_, dcw, w + WDD, 512, dcb, bb + D_, QKVb + 512, QSTR, 1024, 1, 0); // K,V
        fattn_kernel<<<AGRID, 256, 0, stream>>>(QKVb, tin, CTXb, S_, 0);
        g2(CTXb, D_, dcw, w + 3 * WDD, 512, dcb, bb + 3 * D_, P, D_, 512, 0, 0);
        add_ln_kernel<<<M_, 256, 0, stream>>>(Y, Yb, P, dln, ((size_t)l * 3 + 1) * 2 * D_, flagp);
        // FFN
        g4(Yb, D_, dw1, (size_t)l * D_ * HID_, 2048, db1, (size_t)l * HID_, HB, HID_, 2048, 1, 1);
        g2(HB, HID_, dw2, (size_t)l * HID_ * D_, 512, db2, (size_t)l * D_, P, D_, 512, 0, 0);
        add_ln_kernel<<<M_, 256, 0, stream>>>(Y, Yb, P, dln, ((size_t)l * 3 + 2) * 2 * D_, flagp);
    }

    to_out_kernel<<<(out_size + 255) / 256, 256, 0, stream>>>(Y, d_out, out_size, flagp);
}

// Round 2
// 4138.002 us; speedup vs baseline: 1.1243x; 1.1243x over previous
//
#include <hip/hip_runtime.h>
#include <hip/hip_bf16.h>

#define D_   512
#define HID_ 2048
#define NH_  8
#define DH_  64
#define L_   6
#define B_   8
#define S_   512
#define T_   512
#define M_   4096            // B_*S_ rows
#define MD_  (M_ * D_)
#define QSTR 1536            // packed QKV row stride

typedef unsigned short ushort_t;
typedef __attribute__((ext_vector_type(8))) short bf16x8;
typedef __attribute__((ext_vector_type(4))) float f32x4;

__device__ __forceinline__ float bf2f(unsigned short u) {
    union { unsigned int i; float f; } x; x.i = ((unsigned int)u) << 16; return x.f;
}
__device__ __forceinline__ unsigned short f2bf(float f) {
    union { float f; unsigned int u; } x; x.f = f;
    unsigned int r = (x.u + 0x7fffu + ((x.u >> 16) & 1u)) >> 16;
    return (unsigned short)r;
}
// Dual-dtype param loads: mode==1 -> storage f32, mode==0 -> bf16.
__device__ __forceinline__ float ldp(const void* p, size_t i, int mode) {
    return mode ? ((const float*)p)[i] : bf2f(((const unsigned short*)p)[i]);
}

// async global->LDS, 16B per lane; lds dest must be wave-uniform base (+lane*16 implicit)
typedef __attribute__((address_space(1))) const unsigned int GAS_u32;
typedef __attribute__((address_space(3))) unsigned int LAS_u32;
__device__ __forceinline__ void gload16(const void* g, void* l) {
    __builtin_amdgcn_global_load_lds((GAS_u32*)g, (LAS_u32*)l, 16, 0, 0);
}

// ---------------- dtype probe ----------------
__global__ __launch_bounds__(256) void detect_kernel(const void* em, int* flagp) {
    __shared__ int big, zc;
    if (threadIdx.x == 0) { big = 0; zc = 0; }
    __syncthreads();
    const unsigned short* u = (const unsigned short*)em;
    int lbig = 0, lzc = 0;
    for (int i = threadIdx.x; i < 2048; i += 256) {
        unsigned short x = u[512 + i];
        float v = bf2f(x);
        if (!(fabsf(v) < 1000.0f)) lbig = 1;
        if ((((512 + i) & 1) == 0) && ((x & 0x7fff) == 0)) lzc++;
    }
    if (lbig) atomicOr(&big, 1);
    atomicAdd(&zc, lzc);
    __syncthreads();
    if (threadIdx.x == 0) flagp[0] = (big || zc >= 1000) ? 1 : 0;
}

// ---------------- embedding + PE: writes f32 stream + bf16 shadow ----------------
__global__ __launch_bounds__(256) void embed_pe_kernel(const int* __restrict__ tok,
        const void* __restrict__ em, float* __restrict__ out,
        unsigned short* __restrict__ outb, const int* __restrict__ flagp)
{
    const int mode = flagp[0];
    int idx = blockIdx.x * 256 + threadIdx.x;
    int d   = idx & (D_ - 1);
    int row = idx >> 9;
    int s   = row & (S_ - 1);
    int t   = tok[row];
    float e = ldp(em, (size_t)t * D_ + d, mode);
    int d2  = d & ~1;
    float div = expf((float)d2 * (-9.210340371976184f / (float)D_));
    float a   = (float)s * div;
    float pe  = (d & 1) ? cosf(a) : sinf(a);
    float v   = e + pe;
    out[idx]  = v;
    outb[idx] = f2bf(v);
}

// ---------------- bf16 MFMA GEMM, occupancy-first tiling ----------------
// C[M,N] = A[M,K](bf16) @ W[K,N](bf16 or f32 per mode) + bias.
// Block 256 thr = 4 waves (2x2). Wave tile (TMT*16) x (TNT*16), block tile
// TM=TMT*32 x TN=TNT*32, BK=32. Small tiles on purpose: every GEMM here is
// small-N, and at 32x64 wave tiles the grid only delivers 1 wave/SIMD ->
// pure latency-bound (MfmaUtil 3%). 16x32 wave tiles give 4-8x the waves.
// A staged via global_load_lds into linear [TM][32] bf16; W loaded to regs,
// converted, ds_written transposed [n][k] stride 40.
template<int TMT, int TNT>
__global__ __launch_bounds__(256) void mfma_gemm(
        const unsigned short* __restrict__ A, int K,
        const void* __restrict__ W, size_t woff, int nsub,
        const void* __restrict__ bias, size_t boff,
        void* __restrict__ C, int ldc, int cmode /*0=f32,1=bf16*/, int relu,
        const int* __restrict__ flagp)
{
    constexpr int TM  = TMT * 32;
    constexpr int TN  = TNT * 32;
    constexpr int AI  = TM / 16;      // # of 1KB global_load_lds instrs per A tile
    constexpr int TPN = TN / 2;       // threads covering the n-pairs of one k-row group
    constexpr int KR  = TN / 16;      // k-rows per staging thread

    __shared__ unsigned short As[TM * 32];     // linear (gload_lds requirement)
    __shared__ unsigned short Bs[TN * 40];     // [n][k] pad->40

    const int mode = __builtin_amdgcn_readfirstlane(flagp[0]);
    const int tid  = threadIdx.x;
    const int m0   = blockIdx.y * TM;
    const int n0   = blockIdx.x * TN;

    const size_t wbase = woff + (size_t)(n0 / nsub) * (size_t)K * nsub + (n0 % nsub);

    const int lane = tid & 63;
    const int wave = tid >> 6;

    // W staging assignment: thread covers KR k-rows x 2 n-cols
    const int n0t = 2 * (tid % TPN);
    const int kb  = KR * (tid / TPN);

    // wave/lane for MFMA
    const int ln = lane & 15;
    const int q  = lane >> 4;
    const int wm = (wave >> 1) * (TMT * 16);
    const int wn = (wave & 1) * (TNT * 16);

    f32x4 acc[TMT][TNT];
#pragma unroll
    for (int i = 0; i < TMT; ++i)
#pragma unroll
        for (int j = 0; j < TNT; ++j) acc[i][j] = (f32x4)0.0f;

    for (int k0 = 0; k0 < K; k0 += 32) {
        __syncthreads();   // previous compute done; safe to overwrite LDS
        // ---- stage A via async global->LDS ----
#pragma unroll
        for (int u = 0; u < (AI + 3) / 4; ++u) {
            int i = wave + u * 4;            // wave-uniform guard
            if (i < AI) {
                int off = i * 1024 + lane * 16;      // byte offset in A tile
                int row = off >> 6;
                int ke  = (off & 63) >> 1;           // elem offset in 32-elem row
                gload16(A + (size_t)(m0 + row) * K + k0 + ke, &As[i * 512]);
            }
        }
        // ---- stage W tile [32][TN] transposed -> Bs[n][k] ----
        {
            unsigned short lo[KR], hi[KR];
            if (mode == 0) {
                const unsigned short* wp = (const unsigned short*)W + wbase;
#pragma unroll
                for (int r = 0; r < KR; ++r) {
                    unsigned int v = *reinterpret_cast<const unsigned int*>(
                        wp + (size_t)(k0 + kb + r) * nsub + n0t);
                    lo[r] = (unsigned short)(v & 0xffffu);
                    hi[r] = (unsigned short)(v >> 16);
                }
            } else {
                const float* wp = (const float*)W + wbase;
#pragma unroll
                for (int r = 0; r < KR; ++r) {
                    float2 f = *reinterpret_cast<const float2*>(
                        wp + (size_t)(k0 + kb + r) * nsub + n0t);
                    lo[r] = f2bf(f.x); hi[r] = f2bf(f.y);
                }
            }
            unsigned int ul[KR / 2], uh[KR / 2];
#pragma unroll
            for (int p = 0; p < KR / 2; ++p) {
                ul[p] = (unsigned int)lo[2 * p] | ((unsigned int)lo[2 * p + 1] << 16);
                uh[p] = (unsigned int)hi[2 * p] | ((unsigned int)hi[2 * p + 1] << 16);
            }
            if constexpr (KR == 8) {
                *reinterpret_cast<uint4*>(&Bs[(n0t + 0) * 40 + kb]) = make_uint4(ul[0], ul[1], ul[2], ul[3]);
                *reinterpret_cast<uint4*>(&Bs[(n0t + 1) * 40 + kb]) = make_uint4(uh[0], uh[1], uh[2], uh[3]);
            } else if constexpr (KR == 4) {
                *reinterpret_cast<uint2*>(&Bs[(n0t + 0) * 40 + kb]) = make_uint2(ul[0], ul[1]);
                *reinterpret_cast<uint2*>(&Bs[(n0t + 1) * 40 + kb]) = make_uint2(uh[0], uh[1]);
            } else {
                *reinterpret_cast<unsigned int*>(&Bs[(n0t + 0) * 40 + kb]) = ul[0];
                *reinterpret_cast<unsigned int*>(&Bs[(n0t + 1) * 40 + kb]) = uh[0];
            }
        }
        __syncthreads();   // drains gload_lds (vmcnt 0) + ds_writes

        // ---- compute ----
        bf16x8 af[TMT], bfv[TNT];
#pragma unroll
        for (int i = 0; i < TMT; ++i)
            af[i] = *reinterpret_cast<const bf16x8*>(&As[(wm + i * 16 + ln) * 32 + q * 8]);
#pragma unroll
        for (int j = 0; j < TNT; ++j)
            bfv[j] = *reinterpret_cast<const bf16x8*>(&Bs[(wn + j * 16 + ln) * 40 + q * 8]);
#pragma unroll
        for (int i = 0; i < TMT; ++i)
#pragma unroll
            for (int j = 0; j < TNT; ++j)
                acc[i][j] = __builtin_amdgcn_mfma_f32_16x16x32_bf16(af[i], bfv[j], acc[i][j], 0, 0, 0);
    }

    // epilogue: bias (+relu), store f32 or bf16
    float bj[TNT];
#pragma unroll
    for (int j = 0; j < TNT; ++j)
        bj[j] = ldp(bias, boff + (size_t)n0 + wn + j * 16 + ln, mode);
#pragma unroll
    for (int i = 0; i < TMT; ++i) {
#pragma unroll
        for (int j = 0; j < TNT; ++j) {
            int n = n0 + wn + j * 16 + ln;
#pragma unroll
            for (int r = 0; r < 4; ++r) {
                int m = m0 + wm + i * 16 + q * 4 + r;
                float v = acc[i][j][r] + bj[j];
                if (relu) v = fmaxf(v, 0.0f);
                if (cmode == 0) ((float*)C)[(size_t)m * ldc + n] = v;
                else            ((unsigned short*)C)[(size_t)m * ldc + n] = f2bf(v);
            }
        }
    }
}

// ---------------- flash attention (bf16 packed QKV in, bf16 CTX out) ----------------
#define LSTR 68
__global__ __launch_bounds__(256) void fattn_kernel(const unsigned short* __restrict__ QKV,
        const int* __restrict__ kv_tok, unsigned short* __restrict__ O,
        int Sk, int causal)
{
    __shared__ float Qs[64 * LSTR];    // [d][q]
    __shared__ float KVs[64 * LSTR];   // K: [d][k]; V: [k][d]
    __shared__ float Ps[64 * LSTR];    // [q][k]
    int tid = threadIdx.x;
    int bid = blockIdx.x;
    int tq = bid & 7;
    int h  = (bid >> 3) & 7;
    int b  = bid >> 6;
    int q0 = tq * 64;
    const int qg = tid >> 4, kg = tid & 15;
    const int sr = tid >> 2, sc0 = (tid & 3) * 16;

    {   // stage Q transposed
        const unsigned short* p = QKV + (size_t)(b * 512 + q0 + sr) * QSTR + h * DH_ + sc0;
        uint4 u0 = *reinterpret_cast<const uint4*>(p);
        uint4 u1 = *reinterpret_cast<const uint4*>(p + 8);
        unsigned int w[8] = {u0.x, u0.y, u0.z, u0.w, u1.x, u1.y, u1.z, u1.w};
#pragma unroll
        for (int e = 0; e < 8; ++e) {
            Qs[(sc0 + 2 * e + 0) * LSTR + sr] = bf2f((unsigned short)(w[e] & 0xffffu));
            Qs[(sc0 + 2 * e + 1) * LSTR + sr] = bf2f((unsigned short)(w[e] >> 16));
        }
    }

    float m[4], l[4], o[4][4];
#pragma unroll
    for (int i = 0; i < 4; ++i) {
        m[i] = -INFINITY; l[i] = 0.0f;
#pragma unroll
        for (int j = 0; j < 4; ++j) o[i][j] = 0.0f;
    }

    const int nkt = causal ? (tq + 1) : (Sk >> 6);
    for (int kt = 0; kt < nkt; ++kt) {
        int k0 = kt * 64;
        __syncthreads();
        {   // stage K transposed (cols 512..1023 of QKV)
            const unsigned short* p = QKV + (size_t)(b * Sk + k0 + sr) * QSTR + 512 + h * DH_ + sc0;
            uint4 u0 = *reinterpret_cast<const uint4*>(p);
            uint4 u1 = *reinterpret_cast<const uint4*>(p + 8);
            unsigned int w[8] = {u0.x, u0.y, u0.z, u0.w, u1.x, u1.y, u1.z, u1.w};
#pragma unroll
            for (int e = 0; e < 8; ++e) {
                KVs[(sc0 + 2 * e + 0) * LSTR + sr] = bf2f((unsigned short)(w[e] & 0xffffu));
                KVs[(sc0 + 2 * e + 1) * LSTR + sr] = bf2f((unsigned short)(w[e] >> 16));
            }
        }
        __syncthreads();

        float s[4][4] = {};
        for (int d = 0; d < 64; ++d) {
            float4 a4 = *reinterpret_cast<const float4*>(&Qs[d * LSTR + qg * 4]);
            float4 b4 = *reinterpret_cast<const float4*>(&KVs[d * LSTR + kg * 4]);
            float a[4] = {a4.x, a4.y, a4.z, a4.w};
            float bb[4] = {b4.x, b4.y, b4.z, b4.w};
#pragma unroll
            for (int i = 0; i < 4; ++i)
#pragma unroll
                for (int j = 0; j < 4; ++j)
                    s[i][j] = fmaf(a[i], bb[j], s[i][j]);
        }

        int kbase = k0 + kg * 4;
        int tk[4];
#pragma unroll
        for (int j = 0; j < 4; ++j) tk[j] = kv_tok[b * Sk + kbase + j];
#pragma unroll
        for (int i = 0; i < 4; ++i) {
            int qrow = q0 + qg * 4 + i;
#pragma unroll
            for (int j = 0; j < 4; ++j) {
                bool masked = (causal && (kbase + j > qrow)) || (tk[j] == 0);
                s[i][j] = masked ? -INFINITY : s[i][j] * 0.125f;
            }
        }

#pragma unroll
        for (int i = 0; i < 4; ++i) {
            float tm = fmaxf(fmaxf(s[i][0], s[i][1]), fmaxf(s[i][2], s[i][3]));
            tm = fmaxf(tm, __shfl_xor(tm, 1, 16));
            tm = fmaxf(tm, __shfl_xor(tm, 2, 16));
            tm = fmaxf(tm, __shfl_xor(tm, 4, 16));
            tm = fmaxf(tm, __shfl_xor(tm, 8, 16));
            float mnew = fmaxf(m[i], tm);
            float alpha = (mnew == -INFINITY) ? 1.0f : __expf(m[i] - mnew);
            float p[4];
#pragma unroll
            for (int j = 0; j < 4; ++j)
                p[j] = (s[i][j] == -INFINITY) ? 0.0f : __expf(s[i][j] - mnew);
            float4 p4; p4.x = p[0]; p4.y = p[1]; p4.z = p[2]; p4.w = p[3];
            *reinterpret_cast<float4*>(&Ps[(qg * 4 + i) * LSTR + kg * 4]) = p4;
            float rs = p[0] + p[1] + p[2] + p[3];
            rs += __shfl_xor(rs, 1, 16);
            rs += __shfl_xor(rs, 2, 16);
            rs += __shfl_xor(rs, 4, 16);
            rs += __shfl_xor(rs, 8, 16);
            l[i] = l[i] * alpha + rs;
            m[i] = mnew;
#pragma unroll
            for (int j = 0; j < 4; ++j) o[i][j] *= alpha;
        }
        __syncthreads();

        {   // stage V natural [k][d] (cols 1024..1535)
            const unsigned short* p = QKV + (size_t)(b * Sk + k0 + sr) * QSTR + 1024 + h * DH_ + sc0;
            uint4 u0 = *reinterpret_cast<const uint4*>(p);
            uint4 u1 = *reinterpret_cast<const uint4*>(p + 8);
            unsigned int w[8] = {u0.x, u0.y, u0.z, u0.w, u1.x, u1.y, u1.z, u1.w};
#pragma unroll
            for (int e = 0; e < 8; ++e) {
                KVs[sr * LSTR + sc0 + 2 * e + 0] = bf2f((unsigned short)(w[e] & 0xffffu));
                KVs[sr * LSTR + sc0 + 2 * e + 1] = bf2f((unsigned short)(w[e] >> 16));
            }
        }
        __syncthreads();

        for (int k = 0; k < 64; ++k) {
            float4 v4 = *reinterpret_cast<const float4*>(&KVs[k * LSTR + kg * 4]);
            float vv[4] = {v4.x, v4.y, v4.z, v4.w};
            float p0 = Ps[(qg * 4 + 0) * LSTR + k];
            float p1 = Ps[(qg * 4 + 1) * LSTR + k];
            float p2 = Ps[(qg * 4 + 2) * LSTR + k];
            float p3 = Ps[(qg * 4 + 3) * LSTR + k];
#pragma unroll
            for (int j = 0; j < 4; ++j) {
                o[0][j] = fmaf(p0, vv[j], o[0][j]);
                o[1][j] = fmaf(p1, vv[j], o[1][j]);
                o[2][j] = fmaf(p2, vv[j], o[2][j]);
                o[3][j] = fmaf(p3, vv[j], o[3][j]);
            }
        }
    }

#pragma unroll
    for (int i = 0; i < 4; ++i) {
        float inv = (l[i] > 0.0f) ? 1.0f / l[i] : 0.0f;
        ushort4 r;
        r.x = f2bf(o[i][0] * inv); r.y = f2bf(o[i][1] * inv);
        r.z = f2bf(o[i][2] * inv); r.w = f2bf(o[i][3] * inv);
        *reinterpret_cast<ushort4*>(
            &O[(size_t)(b * 512 + q0 + qg * 4 + i) * D_ + h * DH_ + kg * 4]) = r;
    }
}

// ---------------- residual add + LayerNorm: f32 stream + bf16 shadow ----------------
__global__ __launch_bounds__(256) void add_ln_kernel(float* __restrict__ X,
        unsigned short* __restrict__ Xb,
        const float* __restrict__ R, const void* __restrict__ ln, size_t goff,
        const int* __restrict__ flagp)
{
    const int mode = flagp[0];
    __shared__ float red[256];
    int row = blockIdx.x, tid = threadIdx.x;
    size_t base = (size_t)row * D_;
    float v0 = X[base + tid] + R[base + tid];
    float v1 = X[base + 256 + tid] + R[base + 256 + tid];
    red[tid] = v0 + v1; __syncthreads();
    for (int o = 128; o > 0; o >>= 1) {
        if (tid < o) red[tid] += red[tid + o];
        __syncthreads();
    }
    float mu = red[0] * (1.0f / (float)D_);
    __syncthreads();
    float d0 = v0 - mu, d1 = v1 - mu;
    red[tid] = d0 * d0 + d1 * d1; __syncthreads();
    for (int o = 128; o > 0; o >>= 1) {
        if (tid < o) red[tid] += red[tid + o];
        __syncthreads();
    }
    float inv = rsqrtf(red[0] * (1.0f / (float)D_) + 1e-5f);
    float r0 = d0 * inv * ldp(ln, goff + tid, mode)       + ldp(ln, goff + D_ + tid, mode);
    float r1 = d1 * inv * ldp(ln, goff + 256 + tid, mode) + ldp(ln, goff + D_ + 256 + tid, mode);
    X[base + tid] = r0;         Xb[base + tid] = f2bf(r0);
    X[base + 256 + tid] = r1;   Xb[base + 256 + tid] = f2bf(r1);
}

// ---------------- f32 -> output (bf16 or f32 per mode) ----------------
__global__ __launch_bounds__(256) void to_out_kernel(const float* __restrict__ in,
        void* __restrict__ out, int n, const int* __restrict__ flagp)
{
    const int mode = flagp[0];
    int i = blockIdx.x * 256 + threadIdx.x;
    if (i < n) {
        float v = in[i];
        if (mode) ((float*)out)[i] = v;
        else      ((__hip_bfloat16*)out)[i] = __float2bfloat16(v);
    }
}

extern "C" void kernel_launch(void* const* d_in, const int* in_sizes, int n_in,
                              void* d_out, int out_size, void* d_ws, size_t ws_size,
                              hipStream_t stream) {
    const int* tin  = (const int*)d_in[0];
    const int* tout = (const int*)d_in[1];
    const void* emi = d_in[2];
    const void* emo = d_in[3];
    const void* eaw = d_in[4];
    const void* eab = d_in[5];
    const void* eln = d_in[6];
    const void* ew1 = d_in[7];
    const void* eb1 = d_in[8];
    const void* ew2 = d_in[9];
    const void* eb2 = d_in[10];
    const void* dsw = d_in[11];
    const void* dsb = d_in[12];
    const void* dcw = d_in[13];
    const void* dcb = d_in[14];
    const void* dln = d_in[15];
    const void* dw1 = d_in[16];
    const void* db1 = d_in[17];
    const void* dw2 = d_in[18];
    const void* db2 = d_in[19];

    // ws (~48 MB): flag | X,Y,P f32 | Xb,Yb bf16 | QKV(3MD)+CTX(MD) bf16 (HB overlays)
    int*   flagp = (int*)d_ws;
    float* X = (float*)d_ws + 64;
    float* Y = X + MD_;
    float* P = Y + MD_;
    unsigned short* Xb   = (unsigned short*)(P + MD_);
    unsigned short* Yb   = Xb + MD_;
    unsigned short* QKVb = Yb + MD_;
    unsigned short* CTXb = QKVb + 3 * (size_t)MD_;
    unsigned short* HB   = QKVb;   // [M_, 2048] overlays QKV+CTX during FFN

    const size_t WDD = (size_t)D_ * D_;
    const int AGRID = B_ * NH_ * 8;

    // one config everywhere: 32x64 block tile, 16x32 wave tile -> max waves
    auto g = [&](const unsigned short* A, int K, const void* W, size_t woff, int nsub,
                 const void* bias, size_t boff, void* C, int ldc, int N, int cmode, int relu) {
        mfma_gemm<1, 2><<<dim3(N / 64, M_ / 32), 256, 0, stream>>>(
            A, K, W, woff, nsub, bias, boff, C, ldc, cmode, relu, flagp);
    };

    detect_kernel<<<1, 256, 0, stream>>>(emi, flagp);
    embed_pe_kernel<<<(M_ * D_) / 256, 256, 0, stream>>>(tin, emi, X, Xb, flagp);
    embed_pe_kernel<<<(M_ * D_) / 256, 256, 0, stream>>>(tout, emo, Y, Yb, flagp);

    // ---- encoder ----
    for (int l = 0; l < L_; ++l) {
        size_t w = (size_t)l * 4 * WDD, bb = (size_t)l * 4 * D_;
        g(Xb, D_, eaw, w, 512, eab, bb, QKVb, QSTR, 1536, 1, 0);            // fused QKV
        fattn_kernel<<<AGRID, 256, 0, stream>>>(QKVb, tin, CTXb, S_, 0);
        g(CTXb, D_, eaw, w + 3 * WDD, 512, eab, bb + 3 * D_, P, D_, 512, 0, 0);
        add_ln_kernel<<<M_, 256, 0, stream>>>(X, Xb, P, eln, ((size_t)l * 2 + 0) * 2 * D_, flagp);
        g(Xb, D_, ew1, (size_t)l * D_ * HID_, 2048, eb1, (size_t)l * HID_, HB, HID_, 2048, 1, 1);
        g(HB, HID_, ew2, (size_t)l * HID_ * D_, 512, eb2, (size_t)l * D_, P, D_, 512, 0, 0);
        add_ln_kernel<<<M_, 256, 0, stream>>>(X, Xb, P, eln, ((size_t)l * 2 + 1) * 2 * D_, flagp);
    }

    // ---- decoder ----
    for (int l = 0; l < L_; ++l) {
        size_t w = (size_t)l * 4 * WDD, bb = (size_t)l * 4 * D_;
        // self-attention (causal)
        g(Yb, D_, dsw, w, 512, dsb, bb, QKVb, QSTR, 1536, 1, 0);
        fattn_kernel<<<AGRID, 256, 0, stream>>>(QKVb, tout, CTXb, T_, 1);
        g(CTXb, D_, dsw, w + 3 * WDD, 512, dsb, bb + 3 * D_, P, D_, 512, 0, 0);
        add_ln_kernel<<<M_, 256, 0, stream>>>(Y, Yb, P, dln, ((size_t)l * 3 + 0) * 2 * D_, flagp);
        // cross-attention: Q from Y, K/V from X
        g(Yb, D_, dcw, w, 512, dcb, bb, QKVb, QSTR, 512, 1, 0);             // Q -> cols 0..511
        g(Xb, D_, dcw, w + WDD, 512, dcb, bb + D_, QKVb + 512, QSTR, 1024, 1, 0); // K,V
        fattn_kernel<<<AGRID, 256, 0, stream>>>(QKVb, tin, CTXb, S_, 0);
        g(CTXb, D_, dcw, w + 3 * WDD, 512, dcb, bb + 3 * D_, P, D_, 512, 0, 0);
        add_ln_kernel<<<M_, 256, 0, stream>>>(Y, Yb, P, dln, ((size_t)l * 3 + 1) * 2 * D_, flagp);
        // FFN
        g(Yb, D_, dw1, (size_t)l * D_ * HID_, 2048, db1, (size_t)l * HID_, HB, HID_, 2048, 1, 1);
        g(HB, HID_, dw2, (size_t)l * HID_ * D_, 512, db2, (size_t)l * D_, P, D_, 512, 0, 0);
        add_ln_kernel<<<M_, 256, 0, stream>>>(Y, Yb, P, dln, ((size_t)l * 3 + 2) * 2 * D_, flagp);
    }

    to_out_kernel<<<(out_size + 255) / 256, 256, 0, stream>>>(Y, d_out, out_size, flagp);
}

// Round 3
// 3350.297 us; speedup vs baseline: 1.3886x; 1.2351x over previous
//
#include <hip/hip_runtime.h>
#include <hip/hip_bf16.h>

#define D_   512
#define HID_ 2048
#define NH_  8
#define DH_  64
#define L_   6
#define B_   8
#define S_   512
#define T_   512
#define M_   4096            // B_*S_ rows
#define MD_  (M_ * D_)
#define QSTR 1536            // packed QKV row stride

typedef unsigned short ushort_t;
typedef __attribute__((ext_vector_type(8))) short bf16x8;
typedef __attribute__((ext_vector_type(4))) float f32x4;

__device__ __forceinline__ float bf2f(unsigned short u) {
    union { unsigned int i; float f; } x; x.i = ((unsigned int)u) << 16; return x.f;
}
__device__ __forceinline__ unsigned short f2bf(float f) {
    union { float f; unsigned int u; } x; x.f = f;
    unsigned int r = (x.u + 0x7fffu + ((x.u >> 16) & 1u)) >> 16;
    return (unsigned short)r;
}
// Dual-dtype param loads: mode==1 -> storage f32, mode==0 -> bf16.
__device__ __forceinline__ float ldp(const void* p, size_t i, int mode) {
    return mode ? ((const float*)p)[i] : bf2f(((const unsigned short*)p)[i]);
}

// async global->LDS, 16B per lane; lds dest must be wave-uniform base (+lane*16 implicit)
typedef __attribute__((address_space(1))) const unsigned int GAS_u32;
typedef __attribute__((address_space(3))) unsigned int LAS_u32;
__device__ __forceinline__ void gload16(const void* g, void* l) {
    __builtin_amdgcn_global_load_lds((GAS_u32*)g, (LAS_u32*)l, 16, 0, 0);
}

// ---------------- dtype probe ----------------
__global__ __launch_bounds__(256) void detect_kernel(const void* em, int* flagp) {
    __shared__ int big, zc;
    if (threadIdx.x == 0) { big = 0; zc = 0; }
    __syncthreads();
    const unsigned short* u = (const unsigned short*)em;
    int lbig = 0, lzc = 0;
    for (int i = threadIdx.x; i < 2048; i += 256) {
        unsigned short x = u[512 + i];
        float v = bf2f(x);
        if (!(fabsf(v) < 1000.0f)) lbig = 1;
        if ((((512 + i) & 1) == 0) && ((x & 0x7fff) == 0)) lzc++;
    }
    if (lbig) atomicOr(&big, 1);
    atomicAdd(&zc, lzc);
    __syncthreads();
    if (threadIdx.x == 0) flagp[0] = (big || zc >= 1000) ? 1 : 0;
}

// ---------------- embedding + PE: writes f32 stream + bf16 shadow ----------------
__global__ __launch_bounds__(256) void embed_pe_kernel(const int* __restrict__ tok,
        const void* __restrict__ em, float* __restrict__ out,
        unsigned short* __restrict__ outb, const int* __restrict__ flagp)
{
    const int mode = flagp[0];
    int idx = blockIdx.x * 256 + threadIdx.x;
    int d   = idx & (D_ - 1);
    int row = idx >> 9;
    int s   = row & (S_ - 1);
    int t   = tok[row];
    float e = ldp(em, (size_t)t * D_ + d, mode);
    int d2  = d & ~1;
    float div = expf((float)d2 * (-9.210340371976184f / (float)D_));
    float a   = (float)s * div;
    float pe  = (d & 1) ? cosf(a) : sinf(a);
    float v   = e + pe;
    out[idx]  = v;
    outb[idx] = f2bf(v);
}

// ---------------- bf16 MFMA GEMM, occupancy-first tiling ----------------
// C[M,N] = A[M,K](bf16) @ W[K,N](bf16 or f32 per mode) + bias.
// Block 256 thr = 4 waves (2x2). Wave tile (TMT*16) x (TNT*16), block tile
// TM=TMT*32 x TN=TNT*32, BK=32. Small tiles on purpose: every GEMM here is
// small-N; 16x32 wave tiles maximize wave count (TLP over ILP).
// A staged via global_load_lds into linear [TM][32] bf16; W loaded to regs,
// converted, ds_written transposed [n][k] stride 40.
template<int TMT, int TNT>
__global__ __launch_bounds__(256) void mfma_gemm(
        const unsigned short* __restrict__ A, int K,
        const void* __restrict__ W, size_t woff, int nsub,
        const void* __restrict__ bias, size_t boff,
        void* __restrict__ C, int ldc, int cmode /*0=f32,1=bf16*/, int relu,
        const int* __restrict__ flagp)
{
    constexpr int TM  = TMT * 32;
    constexpr int TN  = TNT * 32;
    constexpr int AI  = TM / 16;      // # of 1KB global_load_lds instrs per A tile
    constexpr int TPN = TN / 2;       // threads covering the n-pairs of one k-row group
    constexpr int KR  = TN / 16;      // k-rows per staging thread

    __shared__ unsigned short As[TM * 32];     // linear (gload_lds requirement)
    __shared__ unsigned short Bs[TN * 40];     // [n][k] pad->40

    const int mode = __builtin_amdgcn_readfirstlane(flagp[0]);
    const int tid  = threadIdx.x;
    const int m0   = blockIdx.y * TM;
    const int n0   = blockIdx.x * TN;

    const size_t wbase = woff + (size_t)(n0 / nsub) * (size_t)K * nsub + (n0 % nsub);

    const int lane = tid & 63;
    const int wave = tid >> 6;

    // W staging assignment: thread covers KR k-rows x 2 n-cols
    const int n0t = 2 * (tid % TPN);
    const int kb  = KR * (tid / TPN);

    // wave/lane for MFMA
    const int ln = lane & 15;
    const int q  = lane >> 4;
    const int wm = (wave >> 1) * (TMT * 16);
    const int wn = (wave & 1) * (TNT * 16);

    f32x4 acc[TMT][TNT];
#pragma unroll
    for (int i = 0; i < TMT; ++i)
#pragma unroll
        for (int j = 0; j < TNT; ++j) acc[i][j] = (f32x4)0.0f;

    for (int k0 = 0; k0 < K; k0 += 32) {
        __syncthreads();   // previous compute done; safe to overwrite LDS
        // ---- stage A via async global->LDS ----
#pragma unroll
        for (int u = 0; u < (AI + 3) / 4; ++u) {
            int i = wave + u * 4;            // wave-uniform guard
            if (i < AI) {
                int off = i * 1024 + lane * 16;      // byte offset in A tile
                int row = off >> 6;
                int ke  = (off & 63) >> 1;           // elem offset in 32-elem row
                gload16(A + (size_t)(m0 + row) * K + k0 + ke, &As[i * 512]);
            }
        }
        // ---- stage W tile [32][TN] transposed -> Bs[n][k] ----
        {
            unsigned short lo[KR], hi[KR];
            if (mode == 0) {
                const unsigned short* wp = (const unsigned short*)W + wbase;
#pragma unroll
                for (int r = 0; r < KR; ++r) {
                    unsigned int v = *reinterpret_cast<const unsigned int*>(
                        wp + (size_t)(k0 + kb + r) * nsub + n0t);
                    lo[r] = (unsigned short)(v & 0xffffu);
                    hi[r] = (unsigned short)(v >> 16);
                }
            } else {
                const float* wp = (const float*)W + wbase;
#pragma unroll
                for (int r = 0; r < KR; ++r) {
                    float2 f = *reinterpret_cast<const float2*>(
                        wp + (size_t)(k0 + kb + r) * nsub + n0t);
                    lo[r] = f2bf(f.x); hi[r] = f2bf(f.y);
                }
            }
            unsigned int ul[KR / 2], uh[KR / 2];
#pragma unroll
            for (int p = 0; p < KR / 2; ++p) {
                ul[p] = (unsigned int)lo[2 * p] | ((unsigned int)lo[2 * p + 1] << 16);
                uh[p] = (unsigned int)hi[2 * p] | ((unsigned int)hi[2 * p + 1] << 16);
            }
            if constexpr (KR == 8) {
                *reinterpret_cast<uint4*>(&Bs[(n0t + 0) * 40 + kb]) = make_uint4(ul[0], ul[1], ul[2], ul[3]);
                *reinterpret_cast<uint4*>(&Bs[(n0t + 1) * 40 + kb]) = make_uint4(uh[0], uh[1], uh[2], uh[3]);
            } else if constexpr (KR == 4) {
                *reinterpret_cast<uint2*>(&Bs[(n0t + 0) * 40 + kb]) = make_uint2(ul[0], ul[1]);
                *reinterpret_cast<uint2*>(&Bs[(n0t + 1) * 40 + kb]) = make_uint2(uh[0], uh[1]);
            } else {
                *reinterpret_cast<unsigned int*>(&Bs[(n0t + 0) * 40 + kb]) = ul[0];
                *reinterpret_cast<unsigned int*>(&Bs[(n0t + 1) * 40 + kb]) = uh[0];
            }
        }
        __syncthreads();   // drains gload_lds (vmcnt 0) + ds_writes

        // ---- compute ----
        bf16x8 af[TMT], bfv[TNT];
#pragma unroll
        for (int i = 0; i < TMT; ++i)
            af[i] = *reinterpret_cast<const bf16x8*>(&As[(wm + i * 16 + ln) * 32 + q * 8]);
#pragma unroll
        for (int j = 0; j < TNT; ++j)
            bfv[j] = *reinterpret_cast<const bf16x8*>(&Bs[(wn + j * 16 + ln) * 40 + q * 8]);
#pragma unroll
        for (int i = 0; i < TMT; ++i)
#pragma unroll
            for (int j = 0; j < TNT; ++j)
                acc[i][j] = __builtin_amdgcn_mfma_f32_16x16x32_bf16(af[i], bfv[j], acc[i][j], 0, 0, 0);
    }

    // epilogue: bias (+relu), store f32 or bf16
    float bj[TNT];
#pragma unroll
    for (int j = 0; j < TNT; ++j)
        bj[j] = ldp(bias, boff + (size_t)n0 + wn + j * 16 + ln, mode);
#pragma unroll
    for (int i = 0; i < TMT; ++i) {
#pragma unroll
        for (int j = 0; j < TNT; ++j) {
            int n = n0 + wn + j * 16 + ln;
#pragma unroll
            for (int r = 0; r < 4; ++r) {
                int m = m0 + wm + i * 16 + q * 4 + r;
                float v = acc[i][j][r] + bj[j];
                if (relu) v = fmaxf(v, 0.0f);
                if (cmode == 0) ((float*)C)[(size_t)m * ldc + n] = v;
                else            ((unsigned short*)C)[(size_t)m * ldc + n] = f2bf(v);
            }
        }
    }
}

// ---------------- flash attention (MFMA, bf16 packed QKV in, bf16 CTX out) ----------------
// Block 256 = 4 waves; q-tile 64 (16 rows/wave), k-tile 64, DH=64.
// LDS tiles bf16 [row][64] (128 B rows) with XOR swizzle on 16B slots
// (slot ^= row&7) -> conflict-free ds_read_b128 fragment reads (T2).
// Fragment layouts identical to the GEMM above (verified there):
//   A: row=lane&15, k-slice=(lane>>4)*8;  B: col=lane&15, k-slice=(lane>>4)*8;
//   C/D: col=lane&15, row=(lane>>4)*4+reg.
// Ps is wave-private (each wave writes+reads only its own 16 rows): no barrier.
__device__ __forceinline__ bf16x8 lds_frag(const unsigned short* base, int row, int slot) {
    return *reinterpret_cast<const bf16x8*>(
        (const char*)base + row * 128 + ((slot ^ (row & 7)) << 4));
}

__global__ __launch_bounds__(256) void fattn_kernel(const unsigned short* __restrict__ QKV,
        const int* __restrict__ kv_tok, unsigned short* __restrict__ O,
        int Sk, int causal)
{
    __shared__ unsigned short Qs[64 * 64];   // [q][d]
    __shared__ unsigned short Ks[64 * 64];   // [k][d]
    __shared__ unsigned short Vt[64 * 64];   // [d][k] (transposed)
    __shared__ unsigned short Ps[64 * 64];   // [q][k]

    const int tid = threadIdx.x;
    const int bid = blockIdx.x;
    const int tq = bid & 7;
    const int h  = (bid >> 3) & 7;
    const int b  = bid >> 6;
    const int q0 = tq * 64;

    const int lane = tid & 63;
    const int wave = tid >> 6;
    const int ln   = lane & 15;
    const int g    = lane >> 4;

    const int srow = tid & 63;   // staging row
    const int sslc = tid >> 6;   // staging 16B slice (x2 iters -> 8)

    {   // stage Q [64 q][64 d], swizzled
        const unsigned short* qp = QKV + (size_t)(b * 512 + q0 + srow) * QSTR + h * DH_;
#pragma unroll
        for (int it = 0; it < 2; ++it) {
            int sl = sslc + it * 4;
            uint4 v = *reinterpret_cast<const uint4*>(qp + sl * 8);
            *reinterpret_cast<uint4*>((char*)Qs + srow * 128 + ((sl ^ (srow & 7)) << 4)) = v;
        }
    }

    float mrow[4], lrow[4];
    f32x4 o[4];
#pragma unroll
    for (int r = 0; r < 4; ++r) { mrow[r] = -INFINITY; lrow[r] = 0.0f; }
#pragma unroll
    for (int j = 0; j < 4; ++j) o[j] = (f32x4)0.0f;

    const int nkt = causal ? (tq + 1) : (Sk >> 6);
    for (int kt = 0; kt < nkt; ++kt) {
        const int k0 = kt * 64;
        __syncthreads();   // prev tile's Ks/Vt reads done
        {   // stage K [k][d] + V transposed [d][k]
            const unsigned short* kp = QKV + (size_t)(b * Sk + k0 + srow) * QSTR + 512  + h * DH_;
            const unsigned short* vp = QKV + (size_t)(b * Sk + k0 + srow) * QSTR + 1024 + h * DH_;
#pragma unroll
            for (int it = 0; it < 2; ++it) {
                int sl = sslc + it * 4;
                uint4 kv = *reinterpret_cast<const uint4*>(kp + sl * 8);
                *reinterpret_cast<uint4*>((char*)Ks + srow * 128 + ((sl ^ (srow & 7)) << 4)) = kv;
                uint4 vv = *reinterpret_cast<const uint4*>(vp + sl * 8);
                unsigned int w[4] = {vv.x, vv.y, vv.z, vv.w};
#pragma unroll
                for (int e = 0; e < 8; ++e) {
                    int d = sl * 8 + e;
                    unsigned short val = (e & 1) ? (unsigned short)(w[e >> 1] >> 16)
                                                 : (unsigned short)(w[e >> 1] & 0xffffu);
                    *(unsigned short*)((char*)Vt + d * 128 + (((srow >> 3) ^ (d & 7)) << 4)
                                       + (srow & 7) * 2) = val;
                }
            }
        }
        __syncthreads();

        // ---- QK^T: wave computes S[16 q x 64 k] ----
        f32x4 s[4];
#pragma unroll
        for (int j = 0; j < 4; ++j) s[j] = (f32x4)0.0f;
        __builtin_amdgcn_s_setprio(1);
#pragma unroll
        for (int ks = 0; ks < 2; ++ks) {
            bf16x8 qf = lds_frag(Qs, wave * 16 + ln, g + ks * 4);
#pragma unroll
            for (int j = 0; j < 4; ++j) {
                bf16x8 kf = lds_frag(Ks, j * 16 + ln, g + ks * 4);
                s[j] = __builtin_amdgcn_mfma_f32_16x16x32_bf16(qf, kf, s[j], 0, 0, 0);
            }
        }
        __builtin_amdgcn_s_setprio(0);

        int tk[4];
#pragma unroll
        for (int j = 0; j < 4; ++j) tk[j] = kv_tok[b * Sk + k0 + j * 16 + ln];

        // ---- online softmax (per thread: 4 rows, cols = j*16+ln) ----
#pragma unroll
        for (int r = 0; r < 4; ++r) {
            const int qrow = q0 + wave * 16 + g * 4 + r;
            float sv[4];
#pragma unroll
            for (int j = 0; j < 4; ++j) {
                bool masked = (causal && (k0 + j * 16 + ln > qrow)) || (tk[j] == 0);
                sv[j] = masked ? -INFINITY : s[j][r] * 0.125f;
            }
            float tm = fmaxf(fmaxf(sv[0], sv[1]), fmaxf(sv[2], sv[3]));
            tm = fmaxf(tm, __shfl_xor(tm, 1, 16));
            tm = fmaxf(tm, __shfl_xor(tm, 2, 16));
            tm = fmaxf(tm, __shfl_xor(tm, 4, 16));
            tm = fmaxf(tm, __shfl_xor(tm, 8, 16));
            float mnew = fmaxf(mrow[r], tm);
            float alpha = (mnew == -INFINITY) ? 1.0f : __expf(mrow[r] - mnew);
            float p[4], rs = 0.0f;
#pragma unroll
            for (int j = 0; j < 4; ++j) {
                p[j] = (sv[j] == -INFINITY) ? 0.0f : __expf(sv[j] - mnew);
                rs += p[j];
            }
            rs += __shfl_xor(rs, 1, 16);
            rs += __shfl_xor(rs, 2, 16);
            rs += __shfl_xor(rs, 4, 16);
            rs += __shfl_xor(rs, 8, 16);
            lrow[r] = lrow[r] * alpha + rs;
            mrow[r] = mnew;
#pragma unroll
            for (int j = 0; j < 4; ++j) o[j][r] *= alpha;
            const int prow = wave * 16 + g * 4 + r;
#pragma unroll
            for (int j = 0; j < 4; ++j) {
                int col = j * 16 + ln;
                *(unsigned short*)((char*)Ps + prow * 128 + ((((col >> 3) ^ (prow & 7))) << 4)
                                   + (col & 7) * 2) = f2bf(p[j]);
            }
        }

        // ---- PV: O[16 q x 64 d] += P @ V (Ps rows are wave-private) ----
        __builtin_amdgcn_s_setprio(1);
#pragma unroll
        for (int ks = 0; ks < 2; ++ks) {
            bf16x8 pf = lds_frag(Ps, wave * 16 + ln, g + ks * 4);
#pragma unroll
            for (int j = 0; j < 4; ++j) {
                bf16x8 vf = lds_frag(Vt, j * 16 + ln, g + ks * 4);
                o[j] = __builtin_amdgcn_mfma_f32_16x16x32_bf16(pf, vf, o[j], 0, 0, 0);
            }
        }
        __builtin_amdgcn_s_setprio(0);
    }

    // ---- epilogue: 1/l scaling, bf16 out ----
#pragma unroll
    for (int r = 0; r < 4; ++r) {
        float inv = (lrow[r] > 0.0f) ? 1.0f / lrow[r] : 0.0f;
        int qrow = q0 + wave * 16 + g * 4 + r;
#pragma unroll
        for (int j = 0; j < 4; ++j)
            O[(size_t)(b * 512 + qrow) * D_ + h * DH_ + j * 16 + ln] = f2bf(o[j][r] * inv);
    }
}

// ---------------- residual add + LayerNorm: f32 stream + bf16 shadow ----------------
__global__ __launch_bounds__(256) void add_ln_kernel(float* __restrict__ X,
        unsigned short* __restrict__ Xb,
        const float* __restrict__ R, const void* __restrict__ ln, size_t goff,
        const int* __restrict__ flagp)
{
    const int mode = flagp[0];
    __shared__ float red[256];
    int row = blockIdx.x, tid = threadIdx.x;
    size_t base = (size_t)row * D_;
    float v0 = X[base + tid] + R[base + tid];
    float v1 = X[base + 256 + tid] + R[base + 256 + tid];
    red[tid] = v0 + v1; __syncthreads();
    for (int o = 128; o > 0; o >>= 1) {
        if (tid < o) red[tid] += red[tid + o];
        __syncthreads();
    }
    float mu = red[0] * (1.0f / (float)D_);
    __syncthreads();
    float d0 = v0 - mu, d1 = v1 - mu;
    red[tid] = d0 * d0 + d1 * d1; __syncthreads();
    for (int o = 128; o > 0; o >>= 1) {
        if (tid < o) red[tid] += red[tid + o];
        __syncthreads();
    }
    float inv = rsqrtf(red[0] * (1.0f / (float)D_) + 1e-5f);
    float r0 = d0 * inv * ldp(ln, goff + tid, mode)       + ldp(ln, goff + D_ + tid, mode);
    float r1 = d1 * inv * ldp(ln, goff + 256 + tid, mode) + ldp(ln, goff + D_ + 256 + tid, mode);
    X[base + tid] = r0;         Xb[base + tid] = f2bf(r0);
    X[base + 256 + tid] = r1;   Xb[base + 256 + tid] = f2bf(r1);
}

// ---------------- f32 -> output (bf16 or f32 per mode) ----------------
__global__ __launch_bounds__(256) void to_out_kernel(const float* __restrict__ in,
        void* __restrict__ out, int n, const int* __restrict__ flagp)
{
    const int mode = flagp[0];
    int i = blockIdx.x * 256 + threadIdx.x;
    if (i < n) {
        float v = in[i];
        if (mode) ((float*)out)[i] = v;
        else      ((__hip_bfloat16*)out)[i] = __float2bfloat16(v);
    }
}

extern "C" void kernel_launch(void* const* d_in, const int* in_sizes, int n_in,
                              void* d_out, int out_size, void* d_ws, size_t ws_size,
                              hipStream_t stream) {
    const int* tin  = (const int*)d_in[0];
    const int* tout = (const int*)d_in[1];
    const void* emi = d_in[2];
    const void* emo = d_in[3];
    const void* eaw = d_in[4];
    const void* eab = d_in[5];
    const void* eln = d_in[6];
    const void* ew1 = d_in[7];
    const void* eb1 = d_in[8];
    const void* ew2 = d_in[9];
    const void* eb2 = d_in[10];
    const void* dsw = d_in[11];
    const void* dsb = d_in[12];
    const void* dcw = d_in[13];
    const void* dcb = d_in[14];
    const void* dln = d_in[15];
    const void* dw1 = d_in[16];
    const void* db1 = d_in[17];
    const void* dw2 = d_in[18];
    const void* db2 = d_in[19];

    // ws (~48 MB): flag | X,Y,P f32 | Xb,Yb bf16 | QKV(3MD)+CTX(MD) bf16 (HB overlays)
    int*   flagp = (int*)d_ws;
    float* X = (float*)d_ws + 64;
    float* Y = X + MD_;
    float* P = Y + MD_;
    unsigned short* Xb   = (unsigned short*)(P + MD_);
    unsigned short* Yb   = Xb + MD_;
    unsigned short* QKVb = Yb + MD_;
    unsigned short* CTXb = QKVb + 3 * (size_t)MD_;
    unsigned short* HB   = QKVb;   // [M_, 2048] overlays QKV+CTX during FFN

    const size_t WDD = (size_t)D_ * D_;
    const int AGRID = B_ * NH_ * 8;

    // one config everywhere: 32x64 block tile, 16x32 wave tile -> max waves
    auto g = [&](const unsigned short* A, int K, const void* W, size_t woff, int nsub,
                 const void* bias, size_t boff, void* C, int ldc, int N, int cmode, int relu) {
        mfma_gemm<1, 2><<<dim3(N / 64, M_ / 32), 256, 0, stream>>>(
            A, K, W, woff, nsub, bias, boff, C, ldc, cmode, relu, flagp);
    };

    detect_kernel<<<1, 256, 0, stream>>>(emi, flagp);
    embed_pe_kernel<<<(M_ * D_) / 256, 256, 0, stream>>>(tin, emi, X, Xb, flagp);
    embed_pe_kernel<<<(M_ * D_) / 256, 256, 0, stream>>>(tout, emo, Y, Yb, flagp);

    // ---- encoder ----
    for (int l = 0; l < L_; ++l) {
        size_t w = (size_t)l * 4 * WDD, bb = (size_t)l * 4 * D_;
        g(Xb, D_, eaw, w, 512, eab, bb, QKVb, QSTR, 1536, 1, 0);            // fused QKV
        fattn_kernel<<<AGRID, 256, 0, stream>>>(QKVb, tin, CTXb, S_, 0);
        g(CTXb, D_, eaw, w + 3 * WDD, 512, eab, bb + 3 * D_, P, D_, 512, 0, 0);
        add_ln_kernel<<<M_, 256, 0, stream>>>(X, Xb, P, eln, ((size_t)l * 2 + 0) * 2 * D_, flagp);
        g(Xb, D_, ew1, (size_t)l * D_ * HID_, 2048, eb1, (size_t)l * HID_, HB, HID_, 2048, 1, 1);
        g(HB, HID_, ew2, (size_t)l * HID_ * D_, 512, eb2, (size_t)l * D_, P, D_, 512, 0, 0);
        add_ln_kernel<<<M_, 256, 0, stream>>>(X, Xb, P, eln, ((size_t)l * 2 + 1) * 2 * D_, flagp);
    }

    // ---- decoder ----
    for (int l = 0; l < L_; ++l) {
        size_t w = (size_t)l * 4 * WDD, bb = (size_t)l * 4 * D_;
        // self-attention (causal)
        g(Yb, D_, dsw, w, 512, dsb, bb, QKVb, QSTR, 1536, 1, 0);
        fattn_kernel<<<AGRID, 256, 0, stream>>>(QKVb, tout, CTXb, T_, 1);
        g(CTXb, D_, dsw, w + 3 * WDD, 512, dsb, bb + 3 * D_, P, D_, 512, 0, 0);
        add_ln_kernel<<<M_, 256, 0, stream>>>(Y, Yb, P, dln, ((size_t)l * 3 + 0) * 2 * D_, flagp);
        // cross-attention: Q from Y, K/V from X
        g(Yb, D_, dcw, w, 512, dcb, bb, QKVb, QSTR, 512, 1, 0);             // Q -> cols 0..511
        g(Xb, D_, dcw, w + WDD, 512, dcb, bb + D_, QKVb + 512, QSTR, 1024, 1, 0); // K,V
        fattn_kernel<<<AGRID, 256, 0, stream>>>(QKVb, tin, CTXb, S_, 0);
        g(CTXb, D_, dcw, w + 3 * WDD, 512, dcb, bb + 3 * D_, P, D_, 512, 0, 0);
        add_ln_kernel<<<M_, 256, 0, stream>>>(Y, Yb, P, dln, ((size_t)l * 3 + 1) * 2 * D_, flagp);
        // FFN
        g(Yb, D_, dw1, (size_t)l * D_ * HID_, 2048, db1, (size_t)l * HID_, HB, HID_, 2048, 1, 1);
        g(HB, HID_, dw2, (size_t)l * HID_ * D_, 512, db2, (size_t)l * D_, P, D_, 512, 0, 0);
        add_ln_kernel<<<M_, 256, 0, stream>>>(Y, Yb, P, dln, ((size_t)l * 3 + 2) * 2 * D_, flagp);
    }

    to_out_kernel<<<(out_size + 255) / 256, 256, 0, stream>>>(Y, d_out, out_size, flagp);
}